// Round 13
// baseline (78.171 us; speedup 1.0000x reference)
//
#include <hip/hip_runtime.h>
#include <math.h>

// CasperNet R13: B=131072, D=256, H=64, O=10.
// R9==R12 (63.5 vs 64.5us) despite 2x resident waves -> shared-resource
// bound: phase-2's 256 ds_bpermute + 128 ds_read per wave saturate the
// per-CU LDS pipe (~3-4K cy/wave x 32 waves/CU ~= the whole 152K-cy wall).
// Fix: ROW-PER-LANE cascade with SCALAR-PATH weights:
//  - prep kernel writes UtX[64][80] f32 into d_ws: UtX[i][j] =
//      j<64:  (j>i ? Wh[j][256+i] : (j==i ? bh[i] : 0))   (bias on diag)
//      64<=j<74: Wo[j-64][256+i]  (head coupling),  else 0.
//  - main: each wave does 4 MFMA m-tiles (64 rows x 80 cols, acc=80 VGPR),
//    per-chunk LDS transpose (buffer aliased into sW space; 2-way bank
//    aliases only = free) -> lane l owns row (rowbase+l): a[74].
//  - cascade: h=sigm(a[i]+UtX[i][i]) is LANE-LOCAL (0 bpermutes); updates
//    a[j] += UtX[i][j]*h use wave-uniform weights -> s_load stream through
//    the scalar cache; v_fma v,s,v,v. ZERO LDS ops in the cascade.
//  - full unroll everywhere a[] is touched (rule #20: static indices only).
//  - __launch_bounds__(256,2): 256-VGPR cap >> ~145 peak -> spill impossible.

#define DIMD 256
#define DIMH 64
#define DIMO 10
#define DT   320
#define NT   5        // 5 n-tiles of 16 = 80 cols (74 used)
#define BLOCK 256     // 4 waves
#define TMB  256      // rows per block: 4 waves x 64
#define UTC  80       // UtX row stride (f32)
#define TBS  84       // transpose buffer row stride (f32): 2-way banks only

typedef __attribute__((ext_vector_type(4))) float f32x4;
typedef __attribute__((ext_vector_type(8))) short bf16x8;

__device__ inline unsigned short f2bf(float f) {   // RNE, deterministic
    union { float f; unsigned u; } v; v.f = f;
    unsigned r = v.u + 0x7FFFu + ((v.u >> 16) & 1u);
    return (unsigned short)(r >> 16);
}
__device__ inline float sigm(float s) {
    return __builtin_amdgcn_rcpf(1.0f + __expf(-s));   // v_rcp_f32
}

// ---- prep: transpose cascade/head weights into d_ws (every launch) ----
__global__ void caspernet_prep(const float* __restrict__ Wh,
                               const float* __restrict__ bh,
                               const float* __restrict__ Wo,
                               float* __restrict__ utx)
{
    const int idx = blockIdx.x * 256 + threadIdx.x;
    if (idx >= DIMH * UTC) return;
    const int i = idx / UTC, j = idx % UTC;
    float v = 0.f;
    if (j < DIMH)            v = (j > i) ? Wh[j * DT + DIMD + i]
                                         : ((j == i) ? bh[i] : 0.f);
    else if (j < DIMH + DIMO) v = Wo[(j - DIMH) * DT + DIMD + i];
    utx[idx] = v;
}

__global__ __launch_bounds__(BLOCK, 2) void caspernet_kernel(
    const float* __restrict__ x,    // [B, 256]
    const float* __restrict__ Wh,   // [64, 320]
    const float* __restrict__ Wo,   // [10, 320]
    const float* __restrict__ bo,   // [10]
    const float* __restrict__ utx,  // [64, 80] prepped in d_ws
    float* __restrict__ out,        // [B, 10]
    int B)
{
    // sW (phase 1) and tbuf (transpose) alias: tbuf used only after the
    // post-phase-1 __syncthreads, when sW is dead. 40.96KB total.
    __shared__ short sW[80 * DIMD];                 // bf16 [n][k], swizzled

    const int tid = threadIdx.x;

    // ---- stage W1 = [Wh_x; Wo_x] as bf16, swizzled (as R12) ----
    for (int idx = tid; idx < 80 * 64; idx += BLOCK) {   // 80 rows x 64 float4
        const int n = idx >> 6, k0 = (idx & 63) * 4;
        float4 v = make_float4(0.f, 0.f, 0.f, 0.f);
        if (n < DIMH)      v = *reinterpret_cast<const float4*>(Wh + n * DT + k0);
        else if (n < 74)   v = *reinterpret_cast<const float4*>(Wo + (n - 64) * DT + k0);
        const int kz = k0 ^ ((n & 7) << 3);
        short* d = sW + n * DIMD + kz;
        d[0] = (short)f2bf(v.x); d[1] = (short)f2bf(v.y);
        d[2] = (short)f2bf(v.z); d[3] = (short)f2bf(v.w);
    }
    __syncthreads();

    const int l  = tid & 63;
    const int w  = tid >> 6;            // wave 0..3 -> rows w*64 .. w*64+63
    const int lm = l & 15, lg = l >> 4;
    const size_t rowbase = (size_t)blockIdx.x * TMB + w * 64;

    // ---- phase 1: 4 m-tiles (64 rows) per wave ----
    const float* xr = x + (rowbase + lm) * DIMD + lg * 8;

    f32x4 acc[4][NT];                   // 80 VGPRs
    #pragma unroll
    for (int mt = 0; mt < 4; ++mt)
        #pragma unroll
        for (int t = 0; t < NT; ++t) acc[mt][t] = (f32x4){0.f, 0.f, 0.f, 0.f};

    #pragma unroll 1                    // bound the load window (R7 lesson)
    for (int ks = 0; ks < 8; ++ks) {
        bf16x8 af[4];
        #pragma unroll
        for (int mt = 0; mt < 4; ++mt) {
            const float4 xa = *reinterpret_cast<const float4*>(xr + mt * 16 * DIMD + ks * 32);
            const float4 xb = *reinterpret_cast<const float4*>(xr + mt * 16 * DIMD + ks * 32 + 4);
            af[mt][0] = (short)f2bf(xa.x); af[mt][1] = (short)f2bf(xa.y);
            af[mt][2] = (short)f2bf(xa.z); af[mt][3] = (short)f2bf(xa.w);
            af[mt][4] = (short)f2bf(xb.x); af[mt][5] = (short)f2bf(xb.y);
            af[mt][6] = (short)f2bf(xb.z); af[mt][7] = (short)f2bf(xb.w);
        }
        #pragma unroll
        for (int t = 0; t < NT; ++t) {
            const int n = t * 16 + lm;
            const int kz = (lg * 8 + ks * 32) ^ ((n & 7) << 3);
            const bf16x8 bf = *reinterpret_cast<const bf16x8*>(sW + n * DIMD + kz);
            #pragma unroll
            for (int mt = 0; mt < 4; ++mt)
                acc[mt][t] = __builtin_amdgcn_mfma_f32_16x16x32_bf16(af[mt], bf, acc[mt][t], 0, 0, 0);
        }
    }

    __syncthreads();                    // all waves done reading sW -> alias

    // ---- transpose: per-chunk through LDS; lane l ends owning row l ----
    float* tbuf = reinterpret_cast<float*>(sW) + w * (16 * TBS);  // [16][84]/wave

    float a[74];                        // static-indexed only (rule #20)
    #pragma unroll
    for (int mt = 0; mt < 4; ++mt) {
        #pragma unroll
        for (int t = 0; t < NT; ++t)
            #pragma unroll
            for (int r = 0; r < 4; ++r)
                tbuf[(lg * 4 + r) * TBS + t * 16 + lm] = acc[mt][t][r];
        __syncthreads();                // writes visible (uniform flow)
        if ((l >> 4) == mt) {           // 16 lanes pick up their rows
            const float* tb = tbuf + (l & 15) * TBS;
            #pragma unroll
            for (int j4 = 0; j4 < 18; ++j4) {
                const float4 v = *reinterpret_cast<const float4*>(tb + j4 * 4);
                a[j4 * 4 + 0] = v.x; a[j4 * 4 + 1] = v.y;
                a[j4 * 4 + 2] = v.z; a[j4 * 4 + 3] = v.w;
            }
            const float2 v2 = *reinterpret_cast<const float2*>(tb + 72);
            a[72] = v2.x; a[73] = v2.y;
        }
        __syncthreads();                // reads done before chunk reuse
    }

    // ---- phase 2: lane-local cascade; weights via scalar loads ----
    #pragma unroll
    for (int i = 0; i < DIMH; ++i) {
        const float* uw = utx + i * UTC;          // wave-uniform -> s_load
        const float h = sigm(a[i] + uw[i]);       // bias on the diagonal
        #pragma unroll
        for (int j = i + 1; j < DIMH; ++j)
            a[j] = fmaf(uw[j], h, a[j]);
        #pragma unroll
        for (int c = 0; c < DIMO; ++c)
            a[64 + c] = fmaf(uw[64 + c], h, a[64 + c]);
    }

    // ---- store: lane l writes row (rowbase+l), + bo (uniform s_load) ----
    float* orow = out + (rowbase + l) * DIMO;
    #pragma unroll
    for (int c = 0; c < DIMO / 2; ++c) {
        const float2 v = make_float2(a[64 + 2 * c] + bo[2 * c],
                                     a[65 + 2 * c] + bo[2 * c + 1]);
        *reinterpret_cast<float2*>(orow + 2 * c) = v;
    }
}

extern "C" void kernel_launch(void* const* d_in, const int* in_sizes, int n_in,
                              void* d_out, int out_size, void* d_ws, size_t ws_size,
                              hipStream_t stream) {
    const float* x  = (const float*)d_in[0];
    const float* Wh = (const float*)d_in[1];
    const float* bh = (const float*)d_in[2];
    const float* Wo = (const float*)d_in[3];
    const float* bo = (const float*)d_in[4];
    float* out = (float*)d_out;
    float* utx = (float*)d_ws;                 // 64*80*4 = 20480 B

    const int B = in_sizes[0] / DIMD;          // 131072

    hipLaunchKernelGGL(caspernet_prep, dim3((DIMH * UTC + 255) / 256), dim3(256),
                       0, stream, Wh, bh, Wo, utx);

    const int grid = B / TMB;                  // 512
    hipLaunchKernelGGL(caspernet_kernel, dim3(grid), dim3(BLOCK), 0, stream,
                       x, Wh, Wo, bo, utx, out, B);
}

// Round 15
// 70.893 us; speedup vs baseline: 1.1027x; 1.1027x over previous
//
#include <hip/hip_runtime.h>
#include <math.h>

// CasperNet R15: B=131072, D=256, H=64, O=10.
// R14 (NaN) post-mortem: cvt_pk asm + bf16 weights are the only new
// mechanisms; reverted both. R15 = R12's bit-exact math + a 2-step
// SOFTWARE PIPELINE on the cascade broadcast:
//   invariant entering step i: s_cur = col i pre-act (complete),
//   s_n1 = col i+1 pre-act (complete through step i-1).
//   step i: h = sigm(s_cur); shfl-fetch col i+2 (consumed 2 steps later,
//   so bpermute latency is OFF the serial chain); then
//     s_cur' = fma(c1[i], h, s_n1)   (c1[i] = U[i][i+1])
//     s_n1'  = fma(c2[i], h, tmp)    (c2[i] = U[i][i+2])
//   Same adds, same order as R12's owner-acc path -> bit-identical.
//   c1/c2 from a 512B prep table in d_ws via wave-uniform s_load
//   (scalar-cached; zero LDS ops, zero VALU).
// Serial chain/step: ~90cy (shfl+sigm+fma) -> ~30cy (sigm+fma).
// Config: BLOCK=512, TM=128, grid=1024 (R9 config: 128-VGPR cap, no
// spill at ~60 live regs; LDS 61.7KB -> 2 blocks/CU, 16 waves/CU).
// Wrap-fetch (i+2)&63 at i>=62 is harmless: c2 there is 0.
// Layout (verified R5): MFMA C: col=lane&15, row=(lane>>4)*4+reg.

#define DIMD 256
#define DIMH 64
#define DIMO 10
#define DT   320
#define NT   5        // 5 n-tiles of 16 = 80 cols (74 used)
#define TM   128      // rows per block: 8 waves x 16
#define BLOCK 512

typedef __attribute__((ext_vector_type(4))) float f32x4;
typedef __attribute__((ext_vector_type(8))) short bf16x8;

__device__ inline unsigned short f2bf(float f) {   // RNE, deterministic
    union { float f; unsigned u; } v; v.f = f;
    unsigned r = v.u + 0x7FFFu + ((v.u >> 16) & 1u);
    return (unsigned short)(r >> 16);
}
__device__ inline float sigm(float s) {
    return __builtin_amdgcn_rcpf(1.0f + __expf(-s));   // v_rcp_f32
}

// ---- prep: pipeline coefficients c1[i]=U[i][i+1], c2[i]=U[i][i+2] ----
__global__ void caspernet_prep(const float* __restrict__ Wh,
                               float* __restrict__ cf)
{
    const int i = threadIdx.x;
    if (i >= DIMH) return;
    cf[2 * i]     = (i < DIMH - 1) ? Wh[(i + 1) * DT + DIMD + i] : 0.f;
    cf[2 * i + 1] = (i < DIMH - 2) ? Wh[(i + 2) * DT + DIMD + i] : 0.f;
}

__global__ __launch_bounds__(BLOCK, 2) void caspernet_kernel(
    const float* __restrict__ x,    // [B, 256]
    const float* __restrict__ Wh,   // [64, 320]
    const float* __restrict__ bh,   // [64]
    const float* __restrict__ Wo,   // [10, 320]
    const float* __restrict__ bo,   // [10]
    const float* __restrict__ cf,   // [128] prepped in d_ws
    float* __restrict__ out,        // [B, 10]
    int B)
{
    __shared__ short sW[80 * DIMD];     // bf16 [n][k], k XOR-swizzled; 40960B
    __shared__ f32x4 sU4[DIMH * 16];    // [i][c]: U for cols c+16t;    16384B
    __shared__ float sWoh[DIMH * 16];   // [i][c]: head col c (0 pad);   4096B
    __shared__ float sBias[80];         //                                320B

    const int tid = threadIdx.x;

    // ---- stage W1 = [Wh_x; Wo_x] as bf16, swizzled ----
    for (int idx = tid; idx < 80 * 64; idx += BLOCK) {   // 80 rows x 64 float4
        const int n = idx >> 6, k0 = (idx & 63) * 4;
        float4 v = make_float4(0.f, 0.f, 0.f, 0.f);
        if (n < DIMH)      v = *reinterpret_cast<const float4*>(Wh + n * DT + k0);
        else if (n < 74)   v = *reinterpret_cast<const float4*>(Wo + (n - 64) * DT + k0);
        const int kz = k0 ^ ((n & 7) << 3);
        short* d = sW + n * DIMD + kz;
        d[0] = (short)f2bf(v.x); d[1] = (short)f2bf(v.y);
        d[2] = (short)f2bf(v.z); d[3] = (short)f2bf(v.w);
    }
    // ---- cascade weights (pre-masked, f32) + head + bias ----
    for (int idx = tid; idx < DIMH * 16; idx += BLOCK) {
        const int i = idx >> 4, c = idx & 15;
        f32x4 u;
        u[0] = (c      > i) ? Wh[(c     ) * DT + DIMD + i] : 0.f;
        u[1] = (16 + c > i) ? Wh[(16 + c) * DT + DIMD + i] : 0.f;
        u[2] = (32 + c > i) ? Wh[(32 + c) * DT + DIMD + i] : 0.f;
        u[3] = (48 + c > i) ? Wh[(48 + c) * DT + DIMD + i] : 0.f;
        sU4[idx] = u;
        sWoh[idx] = (c < DIMO) ? Wo[c * DT + DIMD + i] : 0.f;
    }
    if (tid < 80) sBias[tid] = (tid < 64) ? bh[tid] : ((tid < 74) ? bo[tid - 64] : 0.f);
    __syncthreads();

    const int l  = tid & 63;
    const int w  = tid >> 6;            // wave 0..7 -> rows w*16..w*16+15
    const int lm = l & 15, lg = l >> 4;

    // ---- phase 1: one 16-row tile per wave (unchanged) ----
    const size_t rowA = (size_t)blockIdx.x * TM + w * 16 + lm;
    const float* xr = x + rowA * DIMD + lg * 8;

    f32x4 acc[NT];
    #pragma unroll
    for (int t = 0; t < NT; ++t) acc[t] = (f32x4){0.f, 0.f, 0.f, 0.f};

    #pragma unroll
    for (int ks = 0; ks < 8; ++ks) {
        const float4 xa = *reinterpret_cast<const float4*>(xr + ks * 32);
        const float4 xb = *reinterpret_cast<const float4*>(xr + ks * 32 + 4);
        bf16x8 af;
        af[0] = (short)f2bf(xa.x); af[1] = (short)f2bf(xa.y);
        af[2] = (short)f2bf(xa.z); af[3] = (short)f2bf(xa.w);
        af[4] = (short)f2bf(xb.x); af[5] = (short)f2bf(xb.y);
        af[6] = (short)f2bf(xb.z); af[7] = (short)f2bf(xb.w);
        #pragma unroll
        for (int t = 0; t < NT; ++t) {
            const int n = t * 16 + lm;
            const int kz = (lg * 8 + ks * 32) ^ ((n & 7) << 3);
            const bf16x8 bf = *reinterpret_cast<const bf16x8*>(sW + n * DIMD + kz);
            acc[t] = __builtin_amdgcn_mfma_f32_16x16x32_bf16(af, bf, acc[t], 0, 0, 0);
        }
    }
    #pragma unroll
    for (int t = 0; t < NT; ++t) {
        const float bt = sBias[t * 16 + lm];
        acc[t][0] += bt; acc[t][1] += bt; acc[t][2] += bt; acc[t][3] += bt;
    }

    // ---- phase 2: cascade with 2-step-ahead pipelined broadcast ----
    const int gbase = l & 48;
    float scur[4], sn1[4];
    #pragma unroll
    for (int r = 0; r < 4; ++r) scur[r] = __shfl(acc[0][r], gbase | 0, 64);
    #pragma unroll
    for (int r = 0; r < 4; ++r) sn1[r]  = __shfl(acc[0][r], gbase | 1, 64);

    #pragma unroll
    for (int i = 0; i < DIMH; ++i) {
        const float c1 = cf[2 * i];          // wave-uniform -> s_load
        const float c2 = cf[2 * i + 1];
        const int jf = (i + 2) & 63;         // fetch col i+2 (wrap harmless)
        const int tj = jf >> 4, cj = jf & 15;
        const float t0 = __shfl(acc[tj][0], gbase | cj, 64);  // off-chain
        const float t1 = __shfl(acc[tj][1], gbase | cj, 64);
        const float t2 = __shfl(acc[tj][2], gbase | cj, 64);
        const float t3 = __shfl(acc[tj][3], gbase | cj, 64);

        const float h0 = sigm(scur[0]), h1 = sigm(scur[1]);
        const float h2 = sigm(scur[2]), h3 = sigm(scur[3]);

        scur[0] = fmaf(c1, h0, sn1[0]);      // col i+1 now complete
        scur[1] = fmaf(c1, h1, sn1[1]);
        scur[2] = fmaf(c1, h2, sn1[2]);
        scur[3] = fmaf(c1, h3, sn1[3]);
        sn1[0] = fmaf(c2, h0, t0);           // col i+2 complete through i
        sn1[1] = fmaf(c2, h1, t1);
        sn1[2] = fmaf(c2, h2, t2);
        sn1[3] = fmaf(c2, h3, t3);

        const f32x4 uv = sU4[i * 16 + lm];
        const float wo = sWoh[i * 16 + lm];
        const int ti = i >> 4;
        #pragma unroll
        for (int t = ti; t < 4; ++t) {       // cols <= i carry zero weights
            acc[t][0] = fmaf(uv[t], h0, acc[t][0]);
            acc[t][1] = fmaf(uv[t], h1, acc[t][1]);
            acc[t][2] = fmaf(uv[t], h2, acc[t][2]);
            acc[t][3] = fmaf(uv[t], h3, acc[t][3]);
        }
        acc[4][0] = fmaf(wo, h0, acc[4][0]);
        acc[4][1] = fmaf(wo, h1, acc[4][1]);
        acc[4][2] = fmaf(wo, h2, acc[4][2]);
        acc[4][3] = fmaf(wo, h3, acc[4][3]);
    }

    // ---- store head tile (cols 64..73 = C-tile 4) ----
    if (lm < DIMO) {
        const size_t orow0 = (size_t)blockIdx.x * TM + w * 16 + lg * 4;
        #pragma unroll
        for (int r = 0; r < 4; ++r)
            out[(orow0 + r) * DIMO + lm] = acc[4][r];
    }
}

extern "C" void kernel_launch(void* const* d_in, const int* in_sizes, int n_in,
                              void* d_out, int out_size, void* d_ws, size_t ws_size,
                              hipStream_t stream) {
    const float* x  = (const float*)d_in[0];
    const float* Wh = (const float*)d_in[1];
    const float* bh = (const float*)d_in[2];
    const float* Wo = (const float*)d_in[3];
    const float* bo = (const float*)d_in[4];
    float* out = (float*)d_out;
    float* cf  = (float*)d_ws;                 // 128 floats = 512B

    const int B = in_sizes[0] / DIMD;          // 131072

    hipLaunchKernelGGL(caspernet_prep, dim3(1), dim3(64), 0, stream, Wh, cf);

    const int grid = B / TM;                   // 1024
    hipLaunchKernelGGL(caspernet_kernel, dim3(grid), dim3(BLOCK), 0, stream,
                       x, Wh, bh, Wo, bo, cf, out, B);
}

// Round 16
// 49.986 us; speedup vs baseline: 1.5639x; 1.4182x over previous
//
#include <hip/hip_runtime.h>
#include <math.h>

// CasperNet R16: B=131072, D=256, H=64, O=10.
// R9/R12/R15 all ~64-71us: the per-step cascade (64 x {4 shfl + weight
// ds_reads + 20 fma}) is the wall (384 LDS ops/wave). Restructure into
// 4 blocked stages, one per 16-neuron group (= one C-tile):
//   1) transpose tile g via per-wave LDS patch (stride 20: <=2-way = free)
//      -> lane lm holds its row's 16 pre-acts LOCALLY.
//   2) lane-local triangular solve (16 sigm + 120 fma, ZERO cross-lane);
//      16x16 diag weights from 1.9KB d_ws table via wave-uniform s_load
//      (fits 16KB scalar cache; R13 failed with a 20KB table).
//   3) rank-16 update of all future tiles with 16x16x32 bf16 MFMA:
//      A-frag = h (rows are lane-local already), B-frag = U-block bf16
//      staged in LDS (prep-written, loaded linearly). 10 MFMAs total.
// Cascade LDS ops 384 -> 42/wave; cascade VALU ~5.4K -> ~1.8K cy.
// f32 solve; only cross-group h/U are bf16 (R10: bf16 U didn't move absmax).
// No inline asm (R14 lesson). Config: BLOCK=512, TM=128, grid=1024,
// (512,2) -> 128-VGPR cap, live ~85 -> no spill.
// Layout (verified R5): MFMA C: col=lane&15, row=(lane>>4)*4+reg;
// A-frag: lane(lm,lg) = A[row=lm][k=lg*8+j]; B-frag: B[col=n][k].

#define DIMD 256
#define DIMH 64
#define DIMO 10
#define DT   320
#define NT   5        // 5 n-tiles of 16 = 80 cols (74 used)
#define TM   128      // rows per block: 8 waves x 16
#define BLOCK 512
#define UBOFF 2048    // byte offset of B-frag blob in d_ws (16B aligned)

typedef __attribute__((ext_vector_type(4))) float f32x4;
typedef __attribute__((ext_vector_type(8))) short bf16x8;

__device__ inline unsigned short f2bf(float f) {   // RNE, deterministic
    union { float f; unsigned u; } v; v.f = f;
    unsigned r = v.u + 0x7FFFu + ((v.u >> 16) & 1u);
    return (unsigned short)(r >> 16);
}
__device__ inline float sigm(float s) {
    return __builtin_amdgcn_rcpf(1.0f + __expf(-s));   // v_rcp_f32
}

// ---- prep: (a) 480-float tri table cfd[g][k(k-1)/2+m] = U diag blocks;
//            (b) 640 x u16x8 B-frag blob for the 10 (g,t) MFMA slots ----
__global__ void caspernet_prep(const float* __restrict__ Wh,
                               const float* __restrict__ Wo,
                               float* __restrict__ ws)
{
    const int tid = threadIdx.x;
    if (tid < 480) {
        const int g = tid / 120, r = tid % 120;
        int k = 1;
        while (k * (k + 1) / 2 <= r) ++k;          // k(k-1)/2 <= r < k(k+1)/2
        const int m = r - k * (k - 1) / 2;
        ws[tid] = Wh[(g * 16 + k) * DT + DIMD + (g * 16 + m)];
    }
    if (tid < 640) {
        const int p = tid >> 6, l = tid & 63;
        int g, t;
        if      (p < 4) { g = 0; t = p + 1; }
        else if (p < 7) { g = 1; t = p - 2; }      // p=4,5,6 -> t=2,3,4
        else if (p < 9) { g = 2; t = p - 4; }      // p=7,8   -> t=3,4
        else            { g = 3; t = 4;     }
        const int lm = l & 15, lg = l >> 4;
        const int col = t * 16 + lm;
        unsigned short v[8] = {0, 0, 0, 0, 0, 0, 0, 0};
        if (lg < 2) {
            for (int j = 0; j < 8; ++j) {
                const int krow = g * 16 + lg * 8 + j;   // feature 256+krow
                float wv = 0.f;
                if (col < DIMH)      wv = Wh[col * DT + DIMD + krow];
                else if (col < 74)   wv = Wo[(col - DIMH) * DT + DIMD + krow];
                v[j] = f2bf(wv);
            }
        }
        unsigned short* d = (unsigned short*)((char*)ws + UBOFF) + tid * 8;
        for (int j = 0; j < 8; ++j) d[j] = v[j];
    }
}

__global__ __launch_bounds__(BLOCK, 2) void caspernet_kernel(
    const float* __restrict__ x,    // [B, 256]
    const float* __restrict__ Wh,   // [64, 320]
    const float* __restrict__ bh,   // [64]
    const float* __restrict__ Wo,   // [10, 320]
    const float* __restrict__ bo,   // [10]
    const float* __restrict__ cfd,  // d_ws: [480] tri table, then B-frag blob
    float* __restrict__ out,        // [B, 10]
    int B)
{
    __shared__ short sW[80 * DIMD];     // bf16 [n][k], k XOR-swizzled; 40960B
    __shared__ short sUB[640 * 8];      // 10 slots x 64 lanes x u16x8;  10240B
    __shared__ float sT[8][320];        // per-wave 16x20 transpose;     10240B
    __shared__ float sBias[80];         //                                 320B
                                        // total ~61.8KB -> 2 blocks/CU

    const int tid = threadIdx.x;

    // ---- stage W1 = [Wh_x; Wo_x] as bf16, swizzled ----
    for (int idx = tid; idx < 80 * 64; idx += BLOCK) {   // 80 rows x 64 float4
        const int n = idx >> 6, k0 = (idx & 63) * 4;
        float4 v = make_float4(0.f, 0.f, 0.f, 0.f);
        if (n < DIMH)      v = *reinterpret_cast<const float4*>(Wh + n * DT + k0);
        else if (n < 74)   v = *reinterpret_cast<const float4*>(Wo + (n - 64) * DT + k0);
        const int kz = k0 ^ ((n & 7) << 3);
        short* d = sW + n * DIMD + kz;
        d[0] = (short)f2bf(v.x); d[1] = (short)f2bf(v.y);
        d[2] = (short)f2bf(v.z); d[3] = (short)f2bf(v.w);
    }
    // ---- copy prep's B-frag blob into LDS (coalesced b128) ----
    {
        const bf16x8* gUB = reinterpret_cast<const bf16x8*>((const char*)cfd + UBOFF);
        bf16x8* dUB = reinterpret_cast<bf16x8*>(sUB);
        for (int e = tid; e < 640; e += BLOCK) dUB[e] = gUB[e];
    }
    if (tid < 80) sBias[tid] = (tid < 64) ? bh[tid] : ((tid < 74) ? bo[tid - 64] : 0.f);
    __syncthreads();

    const int l  = tid & 63;
    const int w  = tid >> 6;            // wave 0..7 -> rows w*16..w*16+15
    const int lm = l & 15, lg = l >> 4;

    // ---- phase 1: one 16-row tile per wave (R9/R12 structure) ----
    const size_t rowA = (size_t)blockIdx.x * TM + w * 16 + lm;
    const float* xr = x + rowA * DIMD + lg * 8;

    f32x4 acc[NT];
    #pragma unroll
    for (int t = 0; t < NT; ++t) acc[t] = (f32x4){0.f, 0.f, 0.f, 0.f};

    #pragma unroll
    for (int ks = 0; ks < 8; ++ks) {
        const float4 xa = *reinterpret_cast<const float4*>(xr + ks * 32);
        const float4 xb = *reinterpret_cast<const float4*>(xr + ks * 32 + 4);
        bf16x8 af;
        af[0] = (short)f2bf(xa.x); af[1] = (short)f2bf(xa.y);
        af[2] = (short)f2bf(xa.z); af[3] = (short)f2bf(xa.w);
        af[4] = (short)f2bf(xb.x); af[5] = (short)f2bf(xb.y);
        af[6] = (short)f2bf(xb.z); af[7] = (short)f2bf(xb.w);
        #pragma unroll
        for (int t = 0; t < NT; ++t) {
            const int n = t * 16 + lm;
            const int kz = (lg * 8 + ks * 32) ^ ((n & 7) << 3);
            const bf16x8 bf = *reinterpret_cast<const bf16x8*>(sW + n * DIMD + kz);
            acc[t] = __builtin_amdgcn_mfma_f32_16x16x32_bf16(af, bf, acc[t], 0, 0, 0);
        }
    }
    #pragma unroll
    for (int t = 0; t < NT; ++t) {
        const float bt = sBias[t * 16 + lm];
        acc[t][0] += bt; acc[t][1] += bt; acc[t][2] += bt; acc[t][3] += bt;
    }

    // ---- phase 2: blocked cascade, one stage per 16-neuron group ----
    float* tb = &sT[w][0];              // per-wave 16x20 f32 patch
    #pragma unroll
    for (int g = 0; g < 4; ++g) {
        // 1) transpose tile g: C(col=lm, row=lg*4+r) -> tb[row*20+col]
        #pragma unroll
        for (int r = 0; r < 4; ++r)
            tb[(lg * 4 + r) * 20 + lm] = acc[g][r];
        // lane lm picks up its ROW (4 lg copies read same addr = broadcast)
        float s[16];
        #pragma unroll
        for (int q = 0; q < 4; ++q) {
            const f32x4 v = *reinterpret_cast<const f32x4*>(tb + lm * 20 + q * 4);
            s[q * 4 + 0] = v[0]; s[q * 4 + 1] = v[1];
            s[q * 4 + 2] = v[2]; s[q * 4 + 3] = v[3];
        }
        // 2) lane-local triangular solve (weights: wave-uniform s_loads)
        const float* cg = cfd + g * 120;
        float h[16];
        h[0] = sigm(s[0]);
        #pragma unroll
        for (int k = 1; k < 16; ++k) {
            float a_ = s[k];
            #pragma unroll
            for (int m = 0; m < k; ++m)
                a_ = fmaf(cg[k * (k - 1) / 2 + m], h[m], a_);
            h[k] = sigm(a_);
        }
        // 3) A-frag from local h (lg selects k-chunk; lg>=2 are K-pad zeros)
        bf16x8 haf;
        #pragma unroll
        for (int j = 0; j < 8; ++j) {
            const float hv = (lg == 0) ? h[j] : ((lg == 1) ? h[8 + j] : 0.f);
            haf[j] = (short)f2bf(hv);
        }
        // 4) rank-16 MFMA update of all future tiles (incl. head tile 4)
        const int pbase = (g == 0) ? 0 : (g == 1) ? 4 : (g == 2) ? 7 : 9;
        #pragma unroll
        for (int t = g + 1; t < NT; ++t) {
            const bf16x8 bf = *reinterpret_cast<const bf16x8*>(
                sUB + (pbase + t - g - 1) * 512 + l * 8);
            acc[t] = __builtin_amdgcn_mfma_f32_16x16x32_bf16(haf, bf, acc[t], 0, 0, 0);
        }
    }

    // ---- store head tile (cols 64..73 = C-tile 4) ----
    if (lm < DIMO) {
        const size_t orow0 = (size_t)blockIdx.x * TM + w * 16 + lg * 4;
        #pragma unroll
        for (int r = 0; r < 4; ++r)
            out[(orow0 + r) * DIMO + lm] = acc[4][r];
    }
}

extern "C" void kernel_launch(void* const* d_in, const int* in_sizes, int n_in,
                              void* d_out, int out_size, void* d_ws, size_t ws_size,
                              hipStream_t stream) {
    const float* x  = (const float*)d_in[0];
    const float* Wh = (const float*)d_in[1];
    const float* bh = (const float*)d_in[2];
    const float* Wo = (const float*)d_in[3];
    const float* bo = (const float*)d_in[4];
    float* out = (float*)d_out;
    float* ws  = (float*)d_ws;                 // 2048B tri table + 10240B UB

    const int B = in_sizes[0] / DIMD;          // 131072

    hipLaunchKernelGGL(caspernet_prep, dim3(1), dim3(640), 0, stream,
                       Wh, Wo, ws);

    const int grid = B / TM;                   // 1024
    hipLaunchKernelGGL(caspernet_kernel, dim3(grid), dim3(BLOCK), 0, stream,
                       x, Wh, bh, Wo, bo, ws, out, B);
}